// Round 17
// baseline (214.571 us; speedup 1.0000x reference)
//
#include <hip/hip_runtime.h>

// Pipeline: cvt3(x,Wqkv,Wproj) -> GEMM qkv + fused bias/l2norm/scale/split ->
//           prep (bias_prep + v_transpose(+k-perm)) ->
//           flash attn (R14-exact: 8 waves QBLK=128, KV-split x2, (512,6), natural grid)
//           -> GEMM proj (A = (Of0+Of1)/(ls0+ls1) fused in staging, f32 out + bias)
// B=2 L=2048 C=1024 H=16 D=64. All matmuls bf16 MFMA 16x16x32, f32 accumulate.

typedef __bf16 bf16x8 __attribute__((ext_vector_type(8)));
typedef __bf16 bf16x4 __attribute__((ext_vector_type(4)));
typedef float  f32x4  __attribute__((ext_vector_type(4)));

#define BB 2
#define LL 2048
#define CC 1024
#define HH 16
#define DD 64
#define LOG2E 1.44269504088896f

__device__ __forceinline__ f32x4 mfma_16x16x32(bf16x8 a, bf16x8 b, f32x4 c) {
    return __builtin_amdgcn_mfma_f32_16x16x32_bf16(a, b, c, 0, 0, 0);
}

// async global->LDS, 16B per lane; LDS dest = wave-uniform base + lane*16
__device__ __forceinline__ void gload_lds16(const __bf16* g, __bf16* lds) {
    __builtin_amdgcn_global_load_lds(
        (const __attribute__((address_space(1))) unsigned int*)g,
        (__attribute__((address_space(3))) unsigned int*)lds,
        16, 0, 0);
}

__device__ __forceinline__ unsigned pk_bf16(float a, float b) {
    unsigned short ua = __builtin_bit_cast(unsigned short, (__bf16)a);
    unsigned short ub = __builtin_bit_cast(unsigned short, (__bf16)b);
    return (unsigned)ua | ((unsigned)ub << 16);
}

// ---------------- merged f32 -> bf16 convert (x, W_qkv, W_proj in one launch) ------------
__global__ __launch_bounds__(256) void cvt3_kernel(
    const float* __restrict__ x, const float* __restrict__ wq, const float* __restrict__ wp,
    __bf16* __restrict__ xb, __bf16* __restrict__ wqb, __bf16* __restrict__ wpb) {
    const int i = blockIdx.x * 256 + threadIdx.x;   // f32x4 index, 2097152 total
    const float* src; __bf16* dst; int off;
    if (i < 1048576)      { src = x;  dst = xb;  off = i; }
    else if (i < 1835008) { src = wq; dst = wqb; off = i - 1048576; }
    else                  { src = wp; dst = wpb; off = i - 1835008; }
    float4 v = reinterpret_cast<const float4*>(src)[off];
    bf16x4 o;
    o[0] = (__bf16)v.x; o[1] = (__bf16)v.y; o[2] = (__bf16)v.z; o[3] = (__bf16)v.w;
    reinterpret_cast<bf16x4*>(dst)[off] = o;
}

// ---------------- QKV GEMM + fused bias/l2norm/scale/split ----------------
__global__ __launch_bounds__(256) void gemm_qkv_fused_kernel(
    const __bf16* __restrict__ A, const __bf16* __restrict__ Bm,
    const float* __restrict__ q_bias, const float* __restrict__ v_bias,
    const float* __restrict__ scale_mul,
    __bf16* __restrict__ Qw, __bf16* __restrict__ Kw, __bf16* __restrict__ Vw) {
    __shared__ __bf16 As[128 * 64];   // LDS[row][c] = A[row][c ^ ((row&7)<<4)]  (byte view)
    __shared__ __bf16 Bs[128 * 64];
    const int tid = threadIdx.x;
    const int K = 1024;
    const int nwg = gridDim.x * gridDim.y;
    const int flat = blockIdx.y * gridDim.x + blockIdx.x;
    const int wg = (flat & 7) * (nwg >> 3) + (flat >> 3);
    const int m0 = (wg % gridDim.x) * 128, n0 = (wg / gridDim.x) * 128;
    const int w  = tid >> 6, l = tid & 63;
    const int wr = (w >> 1) * 64, wc = (w & 1) * 64;
    const int lr = l & 15, lg = l >> 4;
    const int rmask = (lr & 7) << 4;
    f32x4 acc[4][4] = {};
    const int lrow = l >> 3;
    const int celem = (((l & 7) ^ lrow) << 3);

    for (int kt = 0; kt < K; kt += 64) {
        __syncthreads();
#pragma unroll
        for (int i = 0; i < 4; ++i) {
            const int row = w * 32 + i * 8;
            gload_lds16(A + (size_t)(m0 + row + lrow) * K + kt + celem, &As[row * 64]);
            gload_lds16(Bm + (size_t)(n0 + row + lrow) * K + kt + celem, &Bs[row * 64]);
        }
        asm volatile("s_waitcnt vmcnt(0)" ::: "memory");
        __syncthreads();
#pragma unroll
        for (int kk = 0; kk < 2; ++kk) {
            bf16x8 af[4], bfr[4];
#pragma unroll
            for (int m = 0; m < 4; ++m)
                af[m] = *reinterpret_cast<const bf16x8*>(
                    (char*)As + (wr + m * 16 + lr) * 128 + ((kk * 64 + lg * 16) ^ rmask));
#pragma unroll
            for (int n = 0; n < 4; ++n)
                bfr[n] = *reinterpret_cast<const bf16x8*>(
                    (char*)Bs + (wc + n * 16 + lr) * 128 + ((kk * 64 + lg * 16) ^ rmask));
#pragma unroll
            for (int m = 0; m < 4; ++m)
#pragma unroll
                for (int n = 0; n < 4; ++n)
                    acc[m][n] = mfma_16x16x32(af[m], bfr[n], acc[m][n]);
        }
    }

    // ---- fused epilogue ----
    const int gcbase = n0 + wc;
    const int type = gcbase >> 10;           // 0=q, 1=k, 2=v
    const int h = (gcbase & 1023) >> 6;
    float qscale = 1.0f;
    if (type == 0) qscale = __expf(fminf(scale_mul[h], 4.60517019f)) * LOG2E;
    __bf16* dst = (type == 0) ? Qw : (type == 1) ? Kw : Vw;

#pragma unroll
    for (int m = 0; m < 4; ++m) {
        if (type != 1) {
            const float* bptr = (type == 0) ? q_bias : v_bias;
#pragma unroll
            for (int n = 0; n < 4; ++n) {
                float bv = bptr[(gcbase & 1023) + n * 16 + lr];
#pragma unroll
                for (int r = 0; r < 4; ++r) acc[m][n][r] += bv;
            }
        }
        float rs[4];
        if (type < 2) {
#pragma unroll
            for (int r = 0; r < 4; ++r) {
                float ss = 0.f;
#pragma unroll
                for (int n = 0; n < 4; ++n) ss += acc[m][n][r] * acc[m][n][r];
                rs[r] = ss;
            }
#pragma unroll
            for (int off = 1; off < 16; off <<= 1)
#pragma unroll
                for (int r = 0; r < 4; ++r) rs[r] += __shfl_xor(rs[r], off, 64);
#pragma unroll
            for (int r = 0; r < 4; ++r)
                rs[r] = ((type == 0) ? qscale : 1.0f) / fmaxf(sqrtf(rs[r]), 1e-12f);
        } else {
#pragma unroll
            for (int r = 0; r < 4; ++r) rs[r] = 1.0f;
        }
        const int rowg = m0 + wr + m * 16 + lg * 4;
#pragma unroll
        for (int n = 0; n < 4; ++n) {
            const int d = n * 16 + lr;
#pragma unroll
            for (int r = 0; r < 4; ++r) {
                const int row = rowg + r;
                const int bb = row >> 11, ll = row & 2047;
                dst[((size_t)((bb << 4) + h) * 2048 + ll) * 64 + d] =
                    (__bf16)(acc[m][n][r] * rs[r]);
            }
        }
    }
}

// ---------------- GEMM proj with fused split-combine:
// A[row][c] = (Of0[row][c] + Of1[row][c]) / (ls0[row,h]+ls1[row,h]), cast bf16 in staging.
// B via gload_lds as before. C = A*B^T + bias (f32 out). XCD swz.
__global__ __launch_bounds__(256) void gemm_proj_fused_kernel(
    const float* __restrict__ Of0, const float* __restrict__ Of1,
    const float* __restrict__ lsF, const __bf16* __restrict__ Bm,
    float* __restrict__ Cf, const float* __restrict__ bias) {
    __shared__ __bf16 As[128 * 64];   // LDS[row][c] = A[row][c ^ ((row&7)<<4)] (byte view)
    __shared__ __bf16 Bs[128 * 64];
    const int N = 1024, K = 1024;
    const int tid = threadIdx.x;
    const int nwg = gridDim.x * gridDim.y;
    const int flat = blockIdx.y * gridDim.x + blockIdx.x;
    const int wg = (flat & 7) * (nwg >> 3) + (flat >> 3);
    const int m0 = (wg % gridDim.x) * 128, n0 = (wg / gridDim.x) * 128;
    const int w  = tid >> 6, l = tid & 63;
    const int wr = (w >> 1) * 64, wc = (w & 1) * 64;
    const int lr = l & 15, lg = l >> 4;
    const int rmask = (lr & 7) << 4;
    f32x4 acc[4][4] = {};
    const int lrow = l >> 3;
    const int celem = (((l & 7) ^ lrow) << 3);

    // A reg-staging geometry: thread covers (srow, 32 cols at (tid&1)*32)
    const int srow = tid >> 1;
    const int scb  = (tid & 1) * 64;               // byte col base in 128B row
    const int smask = (srow & 7) << 4;
    const int arow = m0 + srow;                    // global A row (b*2048 + l)
    const size_t lsb = ((size_t)((arow >> 11) << 4)) * 2048 + (arow & 2047); // +h*2048
    const float* a0 = Of0 + (size_t)arow * 1024 + (tid & 1) * 32;
    const float* a1 = Of1 + (size_t)arow * 1024 + (tid & 1) * 32;
    char* asb = (char*)As + srow * 128;

    for (int kt = 0; kt < K; kt += 64) {
        __syncthreads();
        // B stage (async)
#pragma unroll
        for (int i = 0; i < 4; ++i) {
            const int row = w * 32 + i * 8;
            gload_lds16(Bm + (size_t)(n0 + row + lrow) * K + kt + celem, &Bs[row * 64]);
        }
        // A stage: combine + normalize + cvt (32-col chunk lies in head h = kt>>6)
        const int h = kt >> 6;
        const float s0 = lsF[lsb + (size_t)h * 2048];
        const float s1 = lsF[(size_t)32 * 2048 + lsb + (size_t)h * 2048];
        const float inv = 1.0f / (s0 + s1);
        bf16x8 av[4];
#pragma unroll
        for (int j = 0; j < 4; ++j) {
            float4 p0 = reinterpret_cast<const float4*>(a0 + kt + j * 8)[0];
            float4 p1 = reinterpret_cast<const float4*>(a0 + kt + j * 8 + 4)[0];
            float4 q0 = reinterpret_cast<const float4*>(a1 + kt + j * 8)[0];
            float4 q1 = reinterpret_cast<const float4*>(a1 + kt + j * 8 + 4)[0];
            av[j][0] = (__bf16)((p0.x + q0.x) * inv);
            av[j][1] = (__bf16)((p0.y + q0.y) * inv);
            av[j][2] = (__bf16)((p0.z + q0.z) * inv);
            av[j][3] = (__bf16)((p0.w + q0.w) * inv);
            av[j][4] = (__bf16)((p1.x + q1.x) * inv);
            av[j][5] = (__bf16)((p1.y + q1.y) * inv);
            av[j][6] = (__bf16)((p1.z + q1.z) * inv);
            av[j][7] = (__bf16)((p1.w + q1.w) * inv);
        }
#pragma unroll
        for (int j = 0; j < 4; ++j)
            *reinterpret_cast<bf16x8*>(asb + ((scb + j * 16) ^ smask)) = av[j];
        asm volatile("s_waitcnt vmcnt(0)" ::: "memory");
        __syncthreads();
#pragma unroll
        for (int kk = 0; kk < 2; ++kk) {
            bf16x8 af[4], bfr[4];
#pragma unroll
            for (int m = 0; m < 4; ++m)
                af[m] = *reinterpret_cast<const bf16x8*>(
                    (char*)As + (wr + m * 16 + lr) * 128 + ((kk * 64 + lg * 16) ^ rmask));
#pragma unroll
            for (int n = 0; n < 4; ++n)
                bfr[n] = *reinterpret_cast<const bf16x8*>(
                    (char*)Bs + (wc + n * 16 + lr) * 128 + ((kk * 64 + lg * 16) ^ rmask));
#pragma unroll
            for (int m = 0; m < 4; ++m)
#pragma unroll
                for (int n = 0; n < 4; ++n)
                    acc[m][n] = mfma_16x16x32(af[m], bfr[n], acc[m][n]);
        }
    }
#pragma unroll
    for (int m = 0; m < 4; ++m)
#pragma unroll
        for (int n = 0; n < 4; ++n) {
            const int row = m0 + wr + m * 16 + lg * 4;
            const int col = n0 + wc + n * 16 + lr;
#pragma unroll
            for (int r = 0; r < 4; ++r)
                Cf[(size_t)(row + r) * N + col] = acc[m][n][r] + bias[col];
        }
}

// ---------------- merged prep: bias_prep (blocks 0..2047) + v_transpose (2048..3071) ------
__global__ __launch_bounds__(256) void prep_kernel(
    const float* __restrict__ bias, __bf16* __restrict__ bias_bf,
    const __bf16* __restrict__ Vin, __bf16* __restrict__ Vp) {
    const int tid = threadIdx.x;
    if (blockIdx.x < 2048) {
        __shared__ float wmax[4];
        const int l = blockIdx.x;
        const int w = tid >> 6;
        float4 a = reinterpret_cast<const float4*>(bias + (size_t)l * 2048)[tid];
        float4 b = reinterpret_cast<const float4*>(bias + (size_t)l * 2048 + 1024)[tid];
        float m = fmaxf(fmaxf(fmaxf(a.x, a.y), fmaxf(a.z, a.w)),
                        fmaxf(fmaxf(b.x, b.y), fmaxf(b.z, b.w)));
#pragma unroll
        for (int off = 1; off < 64; off <<= 1) m = fmaxf(m, __shfl_xor(m, off, 64));
        if ((tid & 63) == 0) wmax[w] = m;
        __syncthreads();
        float M = fmaxf(fmaxf(wmax[0], wmax[1]), fmaxf(wmax[2], wmax[3]));
        bf16x4 o0, o1;
        o0[0] = (__bf16)((a.x - M) * LOG2E); o0[1] = (__bf16)((a.y - M) * LOG2E);
        o0[2] = (__bf16)((a.z - M) * LOG2E); o0[3] = (__bf16)((a.w - M) * LOG2E);
        o1[0] = (__bf16)((b.x - M) * LOG2E); o1[1] = (__bf16)((b.y - M) * LOG2E);
        o1[2] = (__bf16)((b.z - M) * LOG2E); o1[3] = (__bf16)((b.w - M) * LOG2E);
        reinterpret_cast<bf16x4*>(bias_bf + (size_t)l * 2048)[tid] = o0;
        reinterpret_cast<bf16x4*>(bias_bf + (size_t)l * 2048 + 1024)[tid] = o1;
    } else {
        __shared__ __bf16 T[64][72];
        const int idx = blockIdx.x - 2048;
        const int lb = idx & 31, bh = idx >> 5;
        const size_t base = (size_t)bh * LL * DD;
        const int row = tid >> 2, c = (tid & 3) * 16;
        {
            const __bf16* src = Vin + base + (size_t)(lb * 64 + row) * 64 + c;
            *reinterpret_cast<bf16x8*>(&T[row][c])     = *reinterpret_cast<const bf16x8*>(src);
            *reinterpret_cast<bf16x8*>(&T[row][c + 8]) = *reinterpret_cast<const bf16x8*>(src + 8);
        }
        __syncthreads();
        __bf16 val[16];
#pragma unroll
        for (int jj = 0; jj < 16; ++jj) {
            const int cp = c + jj;
            const int wb = cp & 31;
            const int kloc = (cp & ~31) | (((wb >> 3) & 3) << 2) | (((wb >> 2) & 1) << 4) | (wb & 3);
            val[jj] = T[kloc][row];
        }
        __bf16* dst = Vp + base + (size_t)row * 2048 + lb * 64 + c;
        *reinterpret_cast<bf16x8*>(dst)     = *reinterpret_cast<bf16x8*>(&val[0]);
        *reinterpret_cast<bf16x8*>(dst + 8) = *reinterpret_cast<bf16x8*>(&val[8]);
    }
}

// ---------------- flash attention: R14-exact. 8 waves (512 thr), QBLK=128, KV-split x2 ----
// grid (bh=32, qb=16, sp=2). Fixed-max softmax => partials combine by pure addition.
// NOTE: (512,6) + natural bh-fastest dispatch order is load-bearing (R15 lesson).
__global__ __launch_bounds__(512, 6) void attn_kernel(
    const __bf16* __restrict__ Q, const __bf16* __restrict__ K,
    const __bf16* __restrict__ Vp, const __bf16* __restrict__ biasB,
    float* __restrict__ Of0, float* __restrict__ Of1, float* __restrict__ lsF) {
    __shared__ __bf16 KVs[2][2][64 * 64];   // [buf][K/V]; LDS[row][c]=G[row][c^((row&7)<<4)]
    const int bh = blockIdx.x, qb = blockIdx.y, sp = blockIdx.z;
    const int tid = threadIdx.x;
    const int w = tid >> 6, l = tid & 63;
    const int lr = l & 15, lg = l >> 4;
    const int rmask = (lr & 7) << 4;
    const int b = bh >> 4, h = bh & 15;
    const size_t base = (size_t)bh * LL * DD;
    const int kb0 = sp * 16;

    const int gq = qb * 128 + w * 16 + lr;
    bf16x8 qf[2];
    qf[0] = *reinterpret_cast<const bf16x8*>(Q + base + (size_t)gq * 64 + lg * 8);
    qf[1] = *reinterpret_cast<const bf16x8*>(Q + base + (size_t)gq * 64 + 32 + lg * 8);
    const __bf16* brow = biasB + (size_t)gq * 2048 + lg * 4;

    bf16x8 ones;
#pragma unroll
    for (int j = 0; j < 8; ++j) ones[j] = (__bf16)1.0f;

    // staging: wave w covers rows [w*8, w*8+8); lane: row w*8+(l>>3), 8 elems at (l&7)*8
    const int srow = w * 8 + (l >> 3);
    const int sce  = (l & 7) * 8;                  // element col
    const int smask = (srow & 7) << 4;             // (l>>3)<<4
    const __bf16* kgbase = K  + base + (size_t)srow * 64   + sce;
    const __bf16* vgbase = Vp + base + (size_t)srow * 2048 + sce;

    bf16x8 k0, v0;
    auto stage_regs = [&](int kb) {
        k0 = *reinterpret_cast<const bf16x8*>(kgbase + (size_t)kb * 64 * 64);
        v0 = *reinterpret_cast<const bf16x8*>(vgbase + kb * 64);
    };
    auto write_lds = [&](int buf) {
        *reinterpret_cast<bf16x8*>((char*)KVs[buf][0] + srow * 128 + ((sce * 2) ^ smask)) = k0;
        *reinterpret_cast<bf16x8*>((char*)KVs[buf][1] + srow * 128 + ((sce * 2) ^ smask)) = v0;
    };

    stage_regs(kb0);
    write_lds(0);

    f32x4 Oa[4] = {};
    f32x4 ls = {};
    int cur = 0;

    bf16x4 bcur[4];
#pragma unroll
    for (int t = 0; t < 4; ++t)
        bcur[t] = *reinterpret_cast<const bf16x4*>(brow + kb0 * 64 + t * 16);

    for (int kb = 0; kb < 16; ++kb) {
        __syncthreads();                    // buf[cur] published; buf[cur^1] free
        if (kb < 15) stage_regs(kb0 + kb + 1);

        bf16x4 bnext[4];
        if (kb < 15) {
#pragma unroll
            for (int t = 0; t < 4; ++t)
                bnext[t] = *reinterpret_cast<const bf16x4*>(brow + (kb0 + kb + 1) * 64 + t * 16);
        }

        const char* Kc = (const char*)KVs[cur][0];
        const char* Vc = (const char*)KVs[cur][1];

        // acc init = bias'(bf16); no cexp (cancels in O = sum(pv)/sum(p))
        f32x4 sa[4];
#pragma unroll
        for (int t = 0; t < 4; ++t)
#pragma unroll
            for (int r = 0; r < 4; ++r)
                sa[t][r] = (float)bcur[t][r];

        // S^T·log2e + bias' : lane q=lr, k = 16t+4lg+r
#pragma unroll
        for (int t = 0; t < 4; ++t) {
            const char* kr = Kc + (t * 16 + lr) * 128;
            bf16x8 kf0 = *reinterpret_cast<const bf16x8*>(kr + ((lg * 16) ^ rmask));
            bf16x8 kf1 = *reinterpret_cast<const bf16x8*>(kr + ((64 + lg * 16) ^ rmask));
            sa[t] = mfma_16x16x32(kf0, qf[0], sa[t]);
            sa[t] = mfma_16x16x32(kf1, qf[1], sa[t]);
        }

        // softmax: p = exp2(sa); pack lane-local values into A-operand slots
        float p[4][4];
#pragma unroll
        for (int t = 0; t < 4; ++t)
#pragma unroll
            for (int r = 0; r < 4; ++r)
                p[t][r] = exp2f(sa[t][r]);
        union Upa { unsigned u[4]; bf16x8 v; } pa0, pa1;
        pa0.u[0] = pk_bf16(p[0][0], p[0][1]); pa0.u[1] = pk_bf16(p[0][2], p[0][3]);
        pa0.u[2] = pk_bf16(p[1][0], p[1][1]); pa0.u[3] = pk_bf16(p[1][2], p[1][3]);
        pa1.u[0] = pk_bf16(p[2][0], p[2][1]); pa1.u[1] = pk_bf16(p[2][2], p[2][3]);
        pa1.u[2] = pk_bf16(p[3][0], p[3][1]); pa1.u[3] = pk_bf16(p[3][2], p[3][3]);

        // row-sum via MFMA (B = ones): ls rows = Oa rows
        ls = mfma_16x16x32(pa0.v, ones, ls);
        ls = mfma_16x16x32(pa1.v, ones, ls);

        // O += P·V : V pre-permuted globally -> contiguous b128 reads (same pattern as K)
#pragma unroll
        for (int t = 0; t < 4; ++t) {
            const char* vr = Vc + (t * 16 + lr) * 128;
            bf16x8 vf0 = *reinterpret_cast<const bf16x8*>(vr + ((lg * 16) ^ rmask));
            bf16x8 vf1 = *reinterpret_cast<const bf16x8*>(vr + ((64 + lg * 16) ^ rmask));
            Oa[t] = mfma_16x16x32(pa0.v, vf0, Oa[t]);
            Oa[t] = mfma_16x16x32(pa1.v, vf1, Oa[t]);
        }

        if (kb < 15) {
            write_lds(cur ^ 1);             // write-late; dep on loads forces vmcnt
#pragma unroll
            for (int t = 0; t < 4; ++t) bcur[t] = bnext[t];
        }
        cur ^= 1;
    }

    // partial outputs (no normalization; proj's fused staging divides)
    float* Ofp = sp ? Of1 : Of0;
#pragma unroll
    for (int t = 0; t < 4; ++t)
#pragma unroll
        for (int r = 0; r < 4; ++r) {
            const int row = qb * 128 + w * 16 + lg * 4 + r;
            Ofp[((size_t)(b * 2048 + row)) * 1024 + h * 64 + t * 16 + lr] = Oa[t][r];
        }
    if (lr == 0) {
#pragma unroll
        for (int r = 0; r < 4; ++r) {
            const int row = qb * 128 + w * 16 + lg * 4 + r;
            lsF[((size_t)sp * 32 + bh) * 2048 + row] = ls[r];
        }
    }
}

// ---------------- launch ----------------
extern "C" void kernel_launch(void* const* d_in, const int* in_sizes, int n_in,
                              void* d_out, int out_size, void* d_ws, size_t ws_size,
                              hipStream_t stream) {
    const float* x         = (const float*)d_in[0];
    const float* attn_bias = (const float*)d_in[1];
    const float* W_qkv     = (const float*)d_in[2];
    const float* q_bias    = (const float*)d_in[3];
    const float* v_bias    = (const float*)d_in[4];
    const float* scale_mul = (const float*)d_in[5];
    const float* W_proj    = (const float*)d_in[6];
    const float* b_proj    = (const float*)d_in[7];
    float* out = (float*)d_out;

    char* ws = (char*)d_ws;
    size_t off = 0;
    auto alloc = [&](size_t bytes) {
        void* p = ws + off;
        off = (off + bytes + 255) & ~(size_t)255;
        return p;
    };
    // Vw and xb first: both dead by attn time -> Of partial 0 aliases [0, 16MB)
    __bf16* Vw      = (__bf16*)alloc((size_t)BB * HH * LL * DD * 2);   //  8 MB (off 0)
    __bf16* xb      = (__bf16*)alloc((size_t)4096 * 1024 * 2);         //  8 MB (off 8M)
    __bf16* wqkvb   = (__bf16*)alloc((size_t)3072 * 1024 * 2);         //  6 MB
    __bf16* wprojb  = (__bf16*)alloc((size_t)1024 * 1024 * 2);         //  2 MB
    __bf16* Qw      = (__bf16*)alloc((size_t)BB * HH * LL * DD * 2);   //  8 MB
    __bf16* Kw      = (__bf16*)alloc((size_t)BB * HH * LL * DD * 2);   //  8 MB
    __bf16* biasB   = (__bf16*)alloc((size_t)2048 * 2048 * 2);         //  8 MB
    __bf16* Vp      = (__bf16*)alloc((size_t)BB * HH * LL * DD * 2);   //  8 MB
    float*  Of1     = (float*)alloc((size_t)4096 * 1024 * 4);          // 16 MB (split 1)
    float*  lsF     = (float*)alloc((size_t)2 * 32 * 2048 * 4);        // 0.5 MB
    float*  Of0     = (float*)d_ws;   // split 0 aliases Vw+xb (both dead at attn time)

    cvt3_kernel<<<8192, 256, 0, stream>>>(x, W_qkv, W_proj, xb, wqkvb, wprojb);

    gemm_qkv_fused_kernel<<<dim3(32, 24), 256, 0, stream>>>(
        xb, wqkvb, q_bias, v_bias, scale_mul, Qw, Kw, Vw);

    prep_kernel<<<3072, 256, 0, stream>>>(attn_bias, biasB, Vw, Vp);

    attn_kernel<<<dim3(32, 16, 2), 512, 0, stream>>>(Qw, Kw, Vp, biasB, Of0, Of1, lsF);

    gemm_proj_fused_kernel<<<dim3(32, 8), 256, 0, stream>>>(
        Of0, Of1, lsF, wprojb, out, b_proj);
}

// Round 18
// 182.547 us; speedup vs baseline: 1.1754x; 1.1754x over previous
//
#include <hip/hip_runtime.h>

// Pipeline: cvt3(x,Wqkv,Wproj) -> GEMM qkv + fused bias/l2norm/scale/split ->
//           prep (bias_prep + v_transpose(+k-perm)) ->
//           flash attn (8 waves QBLK=128, KV-split x2, KVBLK=128 paired tiles, (512,4))
//           -> combine partials -> GEMM proj(f32+bias)
// B=2 L=2048 C=1024 H=16 D=64. All matmuls bf16 MFMA 16x16x32, f32 accumulate.

typedef __bf16 bf16x8 __attribute__((ext_vector_type(8)));
typedef __bf16 bf16x4 __attribute__((ext_vector_type(4)));
typedef float  f32x4  __attribute__((ext_vector_type(4)));

#define BB 2
#define LL 2048
#define CC 1024
#define HH 16
#define DD 64
#define LOG2E 1.44269504088896f

__device__ __forceinline__ f32x4 mfma_16x16x32(bf16x8 a, bf16x8 b, f32x4 c) {
    return __builtin_amdgcn_mfma_f32_16x16x32_bf16(a, b, c, 0, 0, 0);
}

// async global->LDS, 16B per lane; LDS dest = wave-uniform base + lane*16
__device__ __forceinline__ void gload_lds16(const __bf16* g, __bf16* lds) {
    __builtin_amdgcn_global_load_lds(
        (const __attribute__((address_space(1))) unsigned int*)g,
        (__attribute__((address_space(3))) unsigned int*)lds,
        16, 0, 0);
}

__device__ __forceinline__ unsigned pk_bf16(float a, float b) {
    unsigned short ua = __builtin_bit_cast(unsigned short, (__bf16)a);
    unsigned short ub = __builtin_bit_cast(unsigned short, (__bf16)b);
    return (unsigned)ua | ((unsigned)ub << 16);
}

// ---------------- merged f32 -> bf16 convert (x, W_qkv, W_proj in one launch) ------------
__global__ __launch_bounds__(256) void cvt3_kernel(
    const float* __restrict__ x, const float* __restrict__ wq, const float* __restrict__ wp,
    __bf16* __restrict__ xb, __bf16* __restrict__ wqb, __bf16* __restrict__ wpb) {
    const int i = blockIdx.x * 256 + threadIdx.x;   // f32x4 index, 2097152 total
    const float* src; __bf16* dst; int off;
    if (i < 1048576)      { src = x;  dst = xb;  off = i; }
    else if (i < 1835008) { src = wq; dst = wqb; off = i - 1048576; }
    else                  { src = wp; dst = wpb; off = i - 1835008; }
    float4 v = reinterpret_cast<const float4*>(src)[off];
    bf16x4 o;
    o[0] = (__bf16)v.x; o[1] = (__bf16)v.y; o[2] = (__bf16)v.z; o[3] = (__bf16)v.w;
    reinterpret_cast<bf16x4*>(dst)[off] = o;
}

// ---------------- QKV GEMM + fused bias/l2norm/scale/split ----------------
__global__ __launch_bounds__(256) void gemm_qkv_fused_kernel(
    const __bf16* __restrict__ A, const __bf16* __restrict__ Bm,
    const float* __restrict__ q_bias, const float* __restrict__ v_bias,
    const float* __restrict__ scale_mul,
    __bf16* __restrict__ Qw, __bf16* __restrict__ Kw, __bf16* __restrict__ Vw) {
    __shared__ __bf16 As[128 * 64];   // LDS[row][c] = A[row][c ^ ((row&7)<<4)]  (byte view)
    __shared__ __bf16 Bs[128 * 64];
    const int tid = threadIdx.x;
    const int K = 1024;
    const int nwg = gridDim.x * gridDim.y;
    const int flat = blockIdx.y * gridDim.x + blockIdx.x;
    const int wg = (flat & 7) * (nwg >> 3) + (flat >> 3);
    const int m0 = (wg % gridDim.x) * 128, n0 = (wg / gridDim.x) * 128;
    const int w  = tid >> 6, l = tid & 63;
    const int wr = (w >> 1) * 64, wc = (w & 1) * 64;
    const int lr = l & 15, lg = l >> 4;
    const int rmask = (lr & 7) << 4;
    f32x4 acc[4][4] = {};
    const int lrow = l >> 3;
    const int celem = (((l & 7) ^ lrow) << 3);

    for (int kt = 0; kt < K; kt += 64) {
        __syncthreads();
#pragma unroll
        for (int i = 0; i < 4; ++i) {
            const int row = w * 32 + i * 8;
            gload_lds16(A + (size_t)(m0 + row + lrow) * K + kt + celem, &As[row * 64]);
            gload_lds16(Bm + (size_t)(n0 + row + lrow) * K + kt + celem, &Bs[row * 64]);
        }
        asm volatile("s_waitcnt vmcnt(0)" ::: "memory");
        __syncthreads();
#pragma unroll
        for (int kk = 0; kk < 2; ++kk) {
            bf16x8 af[4], bfr[4];
#pragma unroll
            for (int m = 0; m < 4; ++m)
                af[m] = *reinterpret_cast<const bf16x8*>(
                    (char*)As + (wr + m * 16 + lr) * 128 + ((kk * 64 + lg * 16) ^ rmask));
#pragma unroll
            for (int n = 0; n < 4; ++n)
                bfr[n] = *reinterpret_cast<const bf16x8*>(
                    (char*)Bs + (wc + n * 16 + lr) * 128 + ((kk * 64 + lg * 16) ^ rmask));
#pragma unroll
            for (int m = 0; m < 4; ++m)
#pragma unroll
                for (int n = 0; n < 4; ++n)
                    acc[m][n] = mfma_16x16x32(af[m], bfr[n], acc[m][n]);
        }
    }

    // ---- fused epilogue ----
    const int gcbase = n0 + wc;
    const int type = gcbase >> 10;           // 0=q, 1=k, 2=v
    const int h = (gcbase & 1023) >> 6;
    float qscale = 1.0f;
    if (type == 0) qscale = __expf(fminf(scale_mul[h], 4.60517019f)) * LOG2E;
    __bf16* dst = (type == 0) ? Qw : (type == 1) ? Kw : Vw;

#pragma unroll
    for (int m = 0; m < 4; ++m) {
        if (type != 1) {
            const float* bptr = (type == 0) ? q_bias : v_bias;
#pragma unroll
            for (int n = 0; n < 4; ++n) {
                float bv = bptr[(gcbase & 1023) + n * 16 + lr];
#pragma unroll
                for (int r = 0; r < 4; ++r) acc[m][n][r] += bv;
            }
        }
        float rs[4];
        if (type < 2) {
#pragma unroll
            for (int r = 0; r < 4; ++r) {
                float ss = 0.f;
#pragma unroll
                for (int n = 0; n < 4; ++n) ss += acc[m][n][r] * acc[m][n][r];
                rs[r] = ss;
            }
#pragma unroll
            for (int off = 1; off < 16; off <<= 1)
#pragma unroll
                for (int r = 0; r < 4; ++r) rs[r] += __shfl_xor(rs[r], off, 64);
#pragma unroll
            for (int r = 0; r < 4; ++r)
                rs[r] = ((type == 0) ? qscale : 1.0f) / fmaxf(sqrtf(rs[r]), 1e-12f);
        } else {
#pragma unroll
            for (int r = 0; r < 4; ++r) rs[r] = 1.0f;
        }
        const int rowg = m0 + wr + m * 16 + lg * 4;
#pragma unroll
        for (int n = 0; n < 4; ++n) {
            const int d = n * 16 + lr;
#pragma unroll
            for (int r = 0; r < 4; ++r) {
                const int row = rowg + r;
                const int bb = row >> 11, ll = row & 2047;
                dst[((size_t)((bb << 4) + h) * 2048 + ll) * 64 + d] =
                    (__bf16)(acc[m][n][r] * rs[r]);
            }
        }
    }
}

// ---------------- GEMM proj: C = A*B^T + bias (f32 out), m97 + XCD swz ----------
__global__ __launch_bounds__(256) void gemm_proj_kernel(
    const __bf16* __restrict__ A, const __bf16* __restrict__ Bm,
    float* __restrict__ Cf, const float* __restrict__ bias, int M, int N, int K) {
    __shared__ __bf16 As[128 * 64];
    __shared__ __bf16 Bs[128 * 64];
    const int tid = threadIdx.x;
    const int nwg = gridDim.x * gridDim.y;
    const int flat = blockIdx.y * gridDim.x + blockIdx.x;
    const int wg = (flat & 7) * (nwg >> 3) + (flat >> 3);
    const int m0 = (wg % gridDim.x) * 128, n0 = (wg / gridDim.x) * 128;
    const int w  = tid >> 6, l = tid & 63;
    const int wr = (w >> 1) * 64, wc = (w & 1) * 64;
    const int lr = l & 15, lg = l >> 4;
    const int rmask = (lr & 7) << 4;
    f32x4 acc[4][4] = {};
    const int lrow = l >> 3;
    const int celem = (((l & 7) ^ lrow) << 3);

    for (int kt = 0; kt < K; kt += 64) {
        __syncthreads();
#pragma unroll
        for (int i = 0; i < 4; ++i) {
            const int row = w * 32 + i * 8;
            gload_lds16(A + (size_t)(m0 + row + lrow) * K + kt + celem, &As[row * 64]);
            gload_lds16(Bm + (size_t)(n0 + row + lrow) * K + kt + celem, &Bs[row * 64]);
        }
        asm volatile("s_waitcnt vmcnt(0)" ::: "memory");
        __syncthreads();
#pragma unroll
        for (int kk = 0; kk < 2; ++kk) {
            bf16x8 af[4], bfr[4];
#pragma unroll
            for (int m = 0; m < 4; ++m)
                af[m] = *reinterpret_cast<const bf16x8*>(
                    (char*)As + (wr + m * 16 + lr) * 128 + ((kk * 64 + lg * 16) ^ rmask));
#pragma unroll
            for (int n = 0; n < 4; ++n)
                bfr[n] = *reinterpret_cast<const bf16x8*>(
                    (char*)Bs + (wc + n * 16 + lr) * 128 + ((kk * 64 + lg * 16) ^ rmask));
#pragma unroll
            for (int m = 0; m < 4; ++m)
#pragma unroll
                for (int n = 0; n < 4; ++n)
                    acc[m][n] = mfma_16x16x32(af[m], bfr[n], acc[m][n]);
        }
    }
#pragma unroll
    for (int m = 0; m < 4; ++m)
#pragma unroll
        for (int n = 0; n < 4; ++n) {
            const int row = m0 + wr + m * 16 + lg * 4;
            const int col = n0 + wc + n * 16 + lr;
#pragma unroll
            for (int r = 0; r < 4; ++r)
                Cf[(size_t)(row + r) * N + col] = acc[m][n][r] + bias[col];
        }
}

// ---------------- merged prep: bias_prep (blocks 0..2047) + v_transpose (2048..3071) ------
__global__ __launch_bounds__(256) void prep_kernel(
    const float* __restrict__ bias, __bf16* __restrict__ bias_bf,
    const __bf16* __restrict__ Vin, __bf16* __restrict__ Vp) {
    const int tid = threadIdx.x;
    if (blockIdx.x < 2048) {
        __shared__ float wmax[4];
        const int l = blockIdx.x;
        const int w = tid >> 6;
        float4 a = reinterpret_cast<const float4*>(bias + (size_t)l * 2048)[tid];
        float4 b = reinterpret_cast<const float4*>(bias + (size_t)l * 2048 + 1024)[tid];
        float m = fmaxf(fmaxf(fmaxf(a.x, a.y), fmaxf(a.z, a.w)),
                        fmaxf(fmaxf(b.x, b.y), fmaxf(b.z, b.w)));
#pragma unroll
        for (int off = 1; off < 64; off <<= 1) m = fmaxf(m, __shfl_xor(m, off, 64));
        if ((tid & 63) == 0) wmax[w] = m;
        __syncthreads();
        float M = fmaxf(fmaxf(wmax[0], wmax[1]), fmaxf(wmax[2], wmax[3]));
        bf16x4 o0, o1;
        o0[0] = (__bf16)((a.x - M) * LOG2E); o0[1] = (__bf16)((a.y - M) * LOG2E);
        o0[2] = (__bf16)((a.z - M) * LOG2E); o0[3] = (__bf16)((a.w - M) * LOG2E);
        o1[0] = (__bf16)((b.x - M) * LOG2E); o1[1] = (__bf16)((b.y - M) * LOG2E);
        o1[2] = (__bf16)((b.z - M) * LOG2E); o1[3] = (__bf16)((b.w - M) * LOG2E);
        reinterpret_cast<bf16x4*>(bias_bf + (size_t)l * 2048)[tid] = o0;
        reinterpret_cast<bf16x4*>(bias_bf + (size_t)l * 2048 + 1024)[tid] = o1;
    } else {
        __shared__ __bf16 T[64][72];
        const int idx = blockIdx.x - 2048;
        const int lb = idx & 31, bh = idx >> 5;
        const size_t base = (size_t)bh * LL * DD;
        const int row = tid >> 2, c = (tid & 3) * 16;
        {
            const __bf16* src = Vin + base + (size_t)(lb * 64 + row) * 64 + c;
            *reinterpret_cast<bf16x8*>(&T[row][c])     = *reinterpret_cast<const bf16x8*>(src);
            *reinterpret_cast<bf16x8*>(&T[row][c + 8]) = *reinterpret_cast<const bf16x8*>(src + 8);
        }
        __syncthreads();
        __bf16 val[16];
#pragma unroll
        for (int jj = 0; jj < 16; ++jj) {
            const int cp = c + jj;
            const int wb = cp & 31;
            const int kloc = (cp & ~31) | (((wb >> 3) & 3) << 2) | (((wb >> 2) & 1) << 4) | (wb & 3);
            val[jj] = T[kloc][row];
        }
        __bf16* dst = Vp + base + (size_t)row * 2048 + lb * 64 + c;
        *reinterpret_cast<bf16x8*>(dst)     = *reinterpret_cast<bf16x8*>(&val[0]);
        *reinterpret_cast<bf16x8*>(dst + 8) = *reinterpret_cast<bf16x8*>(&val[8]);
    }
}

// ---------------- flash attention: 8 waves (512 thr), QBLK=128, KV-split x2,
//                  KVBLK=128 (paired 64x64 tiles, half the barriers), (512,4) ----------
// grid (bh=32, qb=16, sp=2). Each split covers 8 tile-pairs (16 kb-tiles).
// Fixed-max softmax => partials combine by pure addition (separate combine pass).
__global__ __launch_bounds__(512, 4) void attn_kernel(
    const __bf16* __restrict__ Q, const __bf16* __restrict__ K,
    const __bf16* __restrict__ Vp, const __bf16* __restrict__ biasB,
    float* __restrict__ Of0, float* __restrict__ Of1, float* __restrict__ lsF) {
    __shared__ __bf16 KVs[2][2][2][64 * 64];  // [buf][K/V][half]; 64KB; same per-tile swizzle
    const int bh = blockIdx.x, qb = blockIdx.y, sp = blockIdx.z;
    const int tid = threadIdx.x;
    const int w = tid >> 6, l = tid & 63;
    const int lr = l & 15, lg = l >> 4;
    const int rmask = (lr & 7) << 4;
    const int b = bh >> 4, h = bh & 15;
    const size_t base = (size_t)bh * LL * DD;
    const int kb0 = sp * 16;                  // first 64-row tile of this split

    const int gq = qb * 128 + w * 16 + lr;
    bf16x8 qf[2];
    qf[0] = *reinterpret_cast<const bf16x8*>(Q + base + (size_t)gq * 64 + lg * 8);
    qf[1] = *reinterpret_cast<const bf16x8*>(Q + base + (size_t)gq * 64 + 32 + lg * 8);
    const __bf16* brow = biasB + (size_t)gq * 2048 + lg * 4;

    bf16x8 ones;
#pragma unroll
    for (int j = 0; j < 8; ++j) ones[j] = (__bf16)1.0f;

    // staging: per 64x64 tile, wave w covers rows [w*8,+8); lane: row w*8+(l>>3), col (l&7)*8
    const int srow = w * 8 + (l >> 3);
    const int sce  = (l & 7) * 8;
    const int smask = (srow & 7) << 4;
    const __bf16* kgbase = K  + base + (size_t)srow * 64   + sce;
    const __bf16* vgbase = Vp + base + (size_t)srow * 2048 + sce;

    bf16x8 k0, k1, v0, v1;                    // pair staging: tiles 2p, 2p+1
    auto stage_regs = [&](int p) {
        const __bf16* kg = kgbase + (size_t)(kb0 + 2 * p) * 64 * 64;
        k0 = *reinterpret_cast<const bf16x8*>(kg);
        k1 = *reinterpret_cast<const bf16x8*>(kg + 64 * 64);
        const __bf16* vg = vgbase + (kb0 + 2 * p) * 64;
        v0 = *reinterpret_cast<const bf16x8*>(vg);
        v1 = *reinterpret_cast<const bf16x8*>(vg + 64);
    };
    auto write_lds = [&](int buf) {
        const int so = srow * 128 + ((sce * 2) ^ smask);
        *reinterpret_cast<bf16x8*>((char*)KVs[buf][0][0] + so) = k0;
        *reinterpret_cast<bf16x8*>((char*)KVs[buf][0][1] + so) = k1;
        *reinterpret_cast<bf16x8*>((char*)KVs[buf][1][0] + so) = v0;
        *reinterpret_cast<bf16x8*>((char*)KVs[buf][1][1] + so) = v1;
    };

    stage_regs(0);
    write_lds(0);

    f32x4 Oa[4] = {};
    f32x4 ls = {};
    int cur = 0;

    bf16x4 bcur[2][4];
#pragma unroll
    for (int t = 0; t < 4; ++t) {
        bcur[0][t] = *reinterpret_cast<const bf16x4*>(brow + (kb0 + 0) * 64 + t * 16);
        bcur[1][t] = *reinterpret_cast<const bf16x4*>(brow + (kb0 + 1) * 64 + t * 16);
    }

    for (int p = 0; p < 8; ++p) {
        __syncthreads();                      // buf[cur] published; buf[cur^1] free
        if (p < 7) stage_regs(p + 1);

        bf16x4 bnext[2][4];
        if (p < 7) {
#pragma unroll
            for (int t = 0; t < 4; ++t) {
                bnext[0][t] = *reinterpret_cast<const bf16x4*>(brow + (kb0 + 2 * p + 2) * 64 + t * 16);
                bnext[1][t] = *reinterpret_cast<const bf16x4*>(brow + (kb0 + 2 * p + 3) * 64 + t * 16);
            }
        }

#pragma unroll
        for (int half = 0; half < 2; ++half) {
            const char* Kc = (const char*)KVs[cur][0][half];
            const char* Vc = (const char*)KVs[cur][1][half];

            // acc init = bias'(bf16); no cexp (cancels in O = sum(pv)/sum(p))
            f32x4 sa[4];
#pragma unroll
            for (int t = 0; t < 4; ++t)
#pragma unroll
                for (int r = 0; r < 4; ++r)
                    sa[t][r] = (float)bcur[half][t][r];

            // S^T·log2e + bias' : lane q=lr, k = 16t+4lg+r
#pragma unroll
            for (int t = 0; t < 4; ++t) {
                const char* kr = Kc + (t * 16 + lr) * 128;
                bf16x8 kf0 = *reinterpret_cast<const bf16x8*>(kr + ((lg * 16) ^ rmask));
                bf16x8 kf1 = *reinterpret_cast<const bf16x8*>(kr + ((64 + lg * 16) ^ rmask));
                sa[t] = mfma_16x16x32(kf0, qf[0], sa[t]);
                sa[t] = mfma_16x16x32(kf1, qf[1], sa[t]);
            }

            // softmax: p = exp2(sa); pack lane-local values into A-operand slots
            float pv[4][4];
#pragma unroll
            for (int t = 0; t < 4; ++t)
#pragma unroll
                for (int r = 0; r < 4; ++r)
                    pv[t][r] = exp2f(sa[t][r]);
            union Upa { unsigned u[4]; bf16x8 v; } pa0, pa1;
            pa0.u[0] = pk_bf16(pv[0][0], pv[0][1]); pa0.u[1] = pk_bf16(pv[0][2], pv[0][3]);
            pa0.u[2] = pk_bf16(pv[1][0], pv[1][1]); pa0.u[3] = pk_bf16(pv[1][2], pv[1][3]);
            pa1.u[0] = pk_bf16(pv[2][0], pv[2][1]); pa1.u[1] = pk_bf16(pv[2][2], pv[2][3]);
            pa1.u[2] = pk_bf16(pv[3][0], pv[3][1]); pa1.u[3] = pk_bf16(pv[3][2], pv[3][3]);

            // row-sum via MFMA (B = ones): ls rows = Oa rows
            ls = mfma_16x16x32(pa0.v, ones, ls);
            ls = mfma_16x16x32(pa1.v, ones, ls);

            // O += P·V : V pre-permuted globally -> contiguous b128 reads
#pragma unroll
            for (int t = 0; t < 4; ++t) {
                const char* vr = Vc + (t * 16 + lr) * 128;
                bf16x8 vf0 = *reinterpret_cast<const bf16x8*>(vr + ((lg * 16) ^ rmask));
                bf16x8 vf1 = *reinterpret_cast<const bf16x8*>(vr + ((64 + lg * 16) ^ rmask));
                Oa[t] = mfma_16x16x32(pa0.v, vf0, Oa[t]);
                Oa[t] = mfma_16x16x32(pa1.v, vf1, Oa[t]);
            }
        }

        if (p < 7) {
            write_lds(cur ^ 1);               // write-late; dep on loads forces vmcnt
#pragma unroll
            for (int t = 0; t < 4; ++t) {
                bcur[0][t] = bnext[0][t];
                bcur[1][t] = bnext[1][t];
            }
        }
        cur ^= 1;
    }

    // partial outputs (no normalization; combine pass divides)
    float* Ofp = sp ? Of1 : Of0;
#pragma unroll
    for (int t = 0; t < 4; ++t)
#pragma unroll
        for (int r = 0; r < 4; ++r) {
            const int row = qb * 128 + w * 16 + lg * 4 + r;
            Ofp[((size_t)(b * 2048 + row)) * 1024 + h * 64 + t * 16 + lr] = Oa[t][r];
        }
    if (lr == 0) {
#pragma unroll
        for (int r = 0; r < 4; ++r) {
            const int row = qb * 128 + w * 16 + lg * 4 + r;
            lsF[((size_t)sp * 32 + bh) * 2048 + row] = ls[r];
        }
    }
}

// ---------------- combine: Oc = (Of0 + Of1) / (ls0 + ls1), bf16 ----------------
__global__ __launch_bounds__(256) void combine_kernel(
    const float* __restrict__ Of0, const float* __restrict__ Of1,
    const float* __restrict__ lsF, __bf16* __restrict__ Oc) {
    const int i = blockIdx.x * 256 + threadIdx.x;  // f32x4 group, 1M total
    const int e = i * 4;
    const int row = e >> 10;                       // b*2048 + l
    const int col = e & 1023;
    const int h = col >> 6;
    const int b = row >> 11, l = row & 2047;
    const size_t lsi = ((size_t)(b * 16 + h)) * 2048 + l;
    const float inv = 1.0f / (lsF[lsi] + lsF[(size_t)32 * 2048 + lsi]);
    float4 a = reinterpret_cast<const float4*>(Of0)[i];
    float4 c = reinterpret_cast<const float4*>(Of1)[i];
    bf16x4 o;
    o[0] = (__bf16)((a.x + c.x) * inv);
    o[1] = (__bf16)((a.y + c.y) * inv);
    o[2] = (__bf16)((a.z + c.z) * inv);
    o[3] = (__bf16)((a.w + c.w) * inv);
    reinterpret_cast<bf16x4*>(Oc)[i] = o;
}

// ---------------- launch ----------------
extern "C" void kernel_launch(void* const* d_in, const int* in_sizes, int n_in,
                              void* d_out, int out_size, void* d_ws, size_t ws_size,
                              hipStream_t stream) {
    const float* x         = (const float*)d_in[0];
    const float* attn_bias = (const float*)d_in[1];
    const float* W_qkv     = (const float*)d_in[2];
    const float* q_bias    = (const float*)d_in[3];
    const float* v_bias    = (const float*)d_in[4];
    const float* scale_mul = (const float*)d_in[5];
    const float* W_proj    = (const float*)d_in[6];
    const float* b_proj    = (const float*)d_in[7];
    float* out = (float*)d_out;

    char* ws = (char*)d_ws;
    size_t off = 0;
    auto alloc = [&](size_t bytes) {
        void* p = ws + off;
        off = (off + bytes + 255) & ~(size_t)255;
        return p;
    };
    // Vw and xb first: both dead by attn time -> Of partial 0 aliases [0, 16MB)
    __bf16* Vw      = (__bf16*)alloc((size_t)BB * HH * LL * DD * 2);   //  8 MB (off 0)
    __bf16* xb      = (__bf16*)alloc((size_t)4096 * 1024 * 2);         //  8 MB (off 8M)
    __bf16* wqkvb   = (__bf16*)alloc((size_t)3072 * 1024 * 2);         //  6 MB
    __bf16* wprojb  = (__bf16*)alloc((size_t)1024 * 1024 * 2);         //  2 MB
    __bf16* Qw      = (__bf16*)alloc((size_t)BB * HH * LL * DD * 2);   //  8 MB
    __bf16* Kw      = (__bf16*)alloc((size_t)BB * HH * LL * DD * 2);   //  8 MB
    __bf16* Oc      = (__bf16*)alloc((size_t)4096 * 1024 * 2);         //  8 MB
    __bf16* biasB   = (__bf16*)alloc((size_t)2048 * 2048 * 2);         //  8 MB
    __bf16* Vp      = (__bf16*)alloc((size_t)BB * HH * LL * DD * 2);   //  8 MB
    float*  Of1     = (float*)alloc((size_t)4096 * 1024 * 4);          // 16 MB (split 1)
    float*  lsF     = (float*)alloc((size_t)2 * 32 * 2048 * 4);        // 0.5 MB
    float*  Of0     = (float*)d_ws;   // split 0 aliases Vw+xb (both dead at attn time)

    cvt3_kernel<<<8192, 256, 0, stream>>>(x, W_qkv, W_proj, xb, wqkvb, wprojb);

    gemm_qkv_fused_kernel<<<dim3(32, 24), 256, 0, stream>>>(
        xb, wqkvb, q_bias, v_bias, scale_mul, Qw, Kw, Vw);

    prep_kernel<<<3072, 256, 0, stream>>>(attn_bias, biasB, Vw, Vp);

    attn_kernel<<<dim3(32, 16, 2), 512, 0, stream>>>(Qw, Kw, Vp, biasB, Of0, Of1, lsF);

    combine_kernel<<<4096, 256, 0, stream>>>(Of0, Of1, lsF, Oc);

    gemm_proj_kernel<<<dim3(32, 8), 256, 0, stream>>>(
        Oc, wprojb, out, b_proj, 4096, 1024, 1024);
}

// Round 19
// 167.547 us; speedup vs baseline: 1.2807x; 1.0895x over previous
//
#include <hip/hip_runtime.h>

// Pipeline: cvt3(x,Wqkv,Wproj) -> GEMM qkv + fused bias/l2norm/scale/split ->
//           prep (bias_prep + v_transpose(+k-perm)) ->
//           flash attn (8 waves QBLK=128, no KV-split: 512 blocks = exact 2/CU,
//                       normalized bf16 output direct) -> GEMM proj(f32+bias)
// B=2 L=2048 C=1024 H=16 D=64. All matmuls bf16 MFMA 16x16x32, f32 accumulate.

typedef __bf16 bf16x8 __attribute__((ext_vector_type(8)));
typedef __bf16 bf16x4 __attribute__((ext_vector_type(4)));
typedef float  f32x4  __attribute__((ext_vector_type(4)));

#define BB 2
#define LL 2048
#define CC 1024
#define HH 16
#define DD 64
#define LOG2E 1.44269504088896f

__device__ __forceinline__ f32x4 mfma_16x16x32(bf16x8 a, bf16x8 b, f32x4 c) {
    return __builtin_amdgcn_mfma_f32_16x16x32_bf16(a, b, c, 0, 0, 0);
}

// async global->LDS, 16B per lane; LDS dest = wave-uniform base + lane*16
__device__ __forceinline__ void gload_lds16(const __bf16* g, __bf16* lds) {
    __builtin_amdgcn_global_load_lds(
        (const __attribute__((address_space(1))) unsigned int*)g,
        (__attribute__((address_space(3))) unsigned int*)lds,
        16, 0, 0);
}

__device__ __forceinline__ unsigned pk_bf16(float a, float b) {
    unsigned short ua = __builtin_bit_cast(unsigned short, (__bf16)a);
    unsigned short ub = __builtin_bit_cast(unsigned short, (__bf16)b);
    return (unsigned)ua | ((unsigned)ub << 16);
}

// ---------------- merged f32 -> bf16 convert (x, W_qkv, W_proj in one launch) ------------
__global__ __launch_bounds__(256) void cvt3_kernel(
    const float* __restrict__ x, const float* __restrict__ wq, const float* __restrict__ wp,
    __bf16* __restrict__ xb, __bf16* __restrict__ wqb, __bf16* __restrict__ wpb) {
    const int i = blockIdx.x * 256 + threadIdx.x;   // f32x4 index, 2097152 total
    const float* src; __bf16* dst; int off;
    if (i < 1048576)      { src = x;  dst = xb;  off = i; }
    else if (i < 1835008) { src = wq; dst = wqb; off = i - 1048576; }
    else                  { src = wp; dst = wpb; off = i - 1835008; }
    float4 v = reinterpret_cast<const float4*>(src)[off];
    bf16x4 o;
    o[0] = (__bf16)v.x; o[1] = (__bf16)v.y; o[2] = (__bf16)v.z; o[3] = (__bf16)v.w;
    reinterpret_cast<bf16x4*>(dst)[off] = o;
}

// ---------------- QKV GEMM + fused bias/l2norm/scale/split ----------------
__global__ __launch_bounds__(256) void gemm_qkv_fused_kernel(
    const __bf16* __restrict__ A, const __bf16* __restrict__ Bm,
    const float* __restrict__ q_bias, const float* __restrict__ v_bias,
    const float* __restrict__ scale_mul,
    __bf16* __restrict__ Qw, __bf16* __restrict__ Kw, __bf16* __restrict__ Vw) {
    __shared__ __bf16 As[128 * 64];   // LDS[row][c] = A[row][c ^ ((row&7)<<4)]  (byte view)
    __shared__ __bf16 Bs[128 * 64];
    const int tid = threadIdx.x;
    const int K = 1024;
    const int nwg = gridDim.x * gridDim.y;
    const int flat = blockIdx.y * gridDim.x + blockIdx.x;
    const int wg = (flat & 7) * (nwg >> 3) + (flat >> 3);
    const int m0 = (wg % gridDim.x) * 128, n0 = (wg / gridDim.x) * 128;
    const int w  = tid >> 6, l = tid & 63;
    const int wr = (w >> 1) * 64, wc = (w & 1) * 64;
    const int lr = l & 15, lg = l >> 4;
    const int rmask = (lr & 7) << 4;
    f32x4 acc[4][4] = {};
    const int lrow = l >> 3;
    const int celem = (((l & 7) ^ lrow) << 3);

    for (int kt = 0; kt < K; kt += 64) {
        __syncthreads();
#pragma unroll
        for (int i = 0; i < 4; ++i) {
            const int row = w * 32 + i * 8;
            gload_lds16(A + (size_t)(m0 + row + lrow) * K + kt + celem, &As[row * 64]);
            gload_lds16(Bm + (size_t)(n0 + row + lrow) * K + kt + celem, &Bs[row * 64]);
        }
        asm volatile("s_waitcnt vmcnt(0)" ::: "memory");
        __syncthreads();
#pragma unroll
        for (int kk = 0; kk < 2; ++kk) {
            bf16x8 af[4], bfr[4];
#pragma unroll
            for (int m = 0; m < 4; ++m)
                af[m] = *reinterpret_cast<const bf16x8*>(
                    (char*)As + (wr + m * 16 + lr) * 128 + ((kk * 64 + lg * 16) ^ rmask));
#pragma unroll
            for (int n = 0; n < 4; ++n)
                bfr[n] = *reinterpret_cast<const bf16x8*>(
                    (char*)Bs + (wc + n * 16 + lr) * 128 + ((kk * 64 + lg * 16) ^ rmask));
#pragma unroll
            for (int m = 0; m < 4; ++m)
#pragma unroll
                for (int n = 0; n < 4; ++n)
                    acc[m][n] = mfma_16x16x32(af[m], bfr[n], acc[m][n]);
        }
    }

    // ---- fused epilogue ----
    const int gcbase = n0 + wc;
    const int type = gcbase >> 10;           // 0=q, 1=k, 2=v
    const int h = (gcbase & 1023) >> 6;
    float qscale = 1.0f;
    if (type == 0) qscale = __expf(fminf(scale_mul[h], 4.60517019f)) * LOG2E;
    __bf16* dst = (type == 0) ? Qw : (type == 1) ? Kw : Vw;

#pragma unroll
    for (int m = 0; m < 4; ++m) {
        if (type != 1) {
            const float* bptr = (type == 0) ? q_bias : v_bias;
#pragma unroll
            for (int n = 0; n < 4; ++n) {
                float bv = bptr[(gcbase & 1023) + n * 16 + lr];
#pragma unroll
                for (int r = 0; r < 4; ++r) acc[m][n][r] += bv;
            }
        }
        float rs[4];
        if (type < 2) {
#pragma unroll
            for (int r = 0; r < 4; ++r) {
                float ss = 0.f;
#pragma unroll
                for (int n = 0; n < 4; ++n) ss += acc[m][n][r] * acc[m][n][r];
                rs[r] = ss;
            }
#pragma unroll
            for (int off = 1; off < 16; off <<= 1)
#pragma unroll
                for (int r = 0; r < 4; ++r) rs[r] += __shfl_xor(rs[r], off, 64);
#pragma unroll
            for (int r = 0; r < 4; ++r)
                rs[r] = ((type == 0) ? qscale : 1.0f) / fmaxf(sqrtf(rs[r]), 1e-12f);
        } else {
#pragma unroll
            for (int r = 0; r < 4; ++r) rs[r] = 1.0f;
        }
        const int rowg = m0 + wr + m * 16 + lg * 4;
#pragma unroll
        for (int n = 0; n < 4; ++n) {
            const int d = n * 16 + lr;
#pragma unroll
            for (int r = 0; r < 4; ++r) {
                const int row = rowg + r;
                const int bb = row >> 11, ll = row & 2047;
                dst[((size_t)((bb << 4) + h) * 2048 + ll) * 64 + d] =
                    (__bf16)(acc[m][n][r] * rs[r]);
            }
        }
    }
}

// ---------------- GEMM proj: C = A*B^T + bias (f32 out), m97 + XCD swz ----------
__global__ __launch_bounds__(256) void gemm_proj_kernel(
    const __bf16* __restrict__ A, const __bf16* __restrict__ Bm,
    float* __restrict__ Cf, const float* __restrict__ bias, int M, int N, int K) {
    __shared__ __bf16 As[128 * 64];
    __shared__ __bf16 Bs[128 * 64];
    const int tid = threadIdx.x;
    const int nwg = gridDim.x * gridDim.y;
    const int flat = blockIdx.y * gridDim.x + blockIdx.x;
    const int wg = (flat & 7) * (nwg >> 3) + (flat >> 3);
    const int m0 = (wg % gridDim.x) * 128, n0 = (wg / gridDim.x) * 128;
    const int w  = tid >> 6, l = tid & 63;
    const int wr = (w >> 1) * 64, wc = (w & 1) * 64;
    const int lr = l & 15, lg = l >> 4;
    const int rmask = (lr & 7) << 4;
    f32x4 acc[4][4] = {};
    const int lrow = l >> 3;
    const int celem = (((l & 7) ^ lrow) << 3);

    for (int kt = 0; kt < K; kt += 64) {
        __syncthreads();
#pragma unroll
        for (int i = 0; i < 4; ++i) {
            const int row = w * 32 + i * 8;
            gload_lds16(A + (size_t)(m0 + row + lrow) * K + kt + celem, &As[row * 64]);
            gload_lds16(Bm + (size_t)(n0 + row + lrow) * K + kt + celem, &Bs[row * 64]);
        }
        asm volatile("s_waitcnt vmcnt(0)" ::: "memory");
        __syncthreads();
#pragma unroll
        for (int kk = 0; kk < 2; ++kk) {
            bf16x8 af[4], bfr[4];
#pragma unroll
            for (int m = 0; m < 4; ++m)
                af[m] = *reinterpret_cast<const bf16x8*>(
                    (char*)As + (wr + m * 16 + lr) * 128 + ((kk * 64 + lg * 16) ^ rmask));
#pragma unroll
            for (int n = 0; n < 4; ++n)
                bfr[n] = *reinterpret_cast<const bf16x8*>(
                    (char*)Bs + (wc + n * 16 + lr) * 128 + ((kk * 64 + lg * 16) ^ rmask));
#pragma unroll
            for (int m = 0; m < 4; ++m)
#pragma unroll
                for (int n = 0; n < 4; ++n)
                    acc[m][n] = mfma_16x16x32(af[m], bfr[n], acc[m][n]);
        }
    }
#pragma unroll
    for (int m = 0; m < 4; ++m)
#pragma unroll
        for (int n = 0; n < 4; ++n) {
            const int row = m0 + wr + m * 16 + lg * 4;
            const int col = n0 + wc + n * 16 + lr;
#pragma unroll
            for (int r = 0; r < 4; ++r)
                Cf[(size_t)(row + r) * N + col] = acc[m][n][r] + bias[col];
        }
}

// ---------------- merged prep: bias_prep (blocks 0..2047) + v_transpose (2048..3071) ------
__global__ __launch_bounds__(256) void prep_kernel(
    const float* __restrict__ bias, __bf16* __restrict__ bias_bf,
    const __bf16* __restrict__ Vin, __bf16* __restrict__ Vp) {
    const int tid = threadIdx.x;
    if (blockIdx.x < 2048) {
        __shared__ float wmax[4];
        const int l = blockIdx.x;
        const int w = tid >> 6;
        float4 a = reinterpret_cast<const float4*>(bias + (size_t)l * 2048)[tid];
        float4 b = reinterpret_cast<const float4*>(bias + (size_t)l * 2048 + 1024)[tid];
        float m = fmaxf(fmaxf(fmaxf(a.x, a.y), fmaxf(a.z, a.w)),
                        fmaxf(fmaxf(b.x, b.y), fmaxf(b.z, b.w)));
#pragma unroll
        for (int off = 1; off < 64; off <<= 1) m = fmaxf(m, __shfl_xor(m, off, 64));
        if ((tid & 63) == 0) wmax[w] = m;
        __syncthreads();
        float M = fmaxf(fmaxf(wmax[0], wmax[1]), fmaxf(wmax[2], wmax[3]));
        bf16x4 o0, o1;
        o0[0] = (__bf16)((a.x - M) * LOG2E); o0[1] = (__bf16)((a.y - M) * LOG2E);
        o0[2] = (__bf16)((a.z - M) * LOG2E); o0[3] = (__bf16)((a.w - M) * LOG2E);
        o1[0] = (__bf16)((b.x - M) * LOG2E); o1[1] = (__bf16)((b.y - M) * LOG2E);
        o1[2] = (__bf16)((b.z - M) * LOG2E); o1[3] = (__bf16)((b.w - M) * LOG2E);
        reinterpret_cast<bf16x4*>(bias_bf + (size_t)l * 2048)[tid] = o0;
        reinterpret_cast<bf16x4*>(bias_bf + (size_t)l * 2048 + 1024)[tid] = o1;
    } else {
        __shared__ __bf16 T[64][72];
        const int idx = blockIdx.x - 2048;
        const int lb = idx & 31, bh = idx >> 5;
        const size_t base = (size_t)bh * LL * DD;
        const int row = tid >> 2, c = (tid & 3) * 16;
        {
            const __bf16* src = Vin + base + (size_t)(lb * 64 + row) * 64 + c;
            *reinterpret_cast<bf16x8*>(&T[row][c])     = *reinterpret_cast<const bf16x8*>(src);
            *reinterpret_cast<bf16x8*>(&T[row][c + 8]) = *reinterpret_cast<const bf16x8*>(src + 8);
        }
        __syncthreads();
        __bf16 val[16];
#pragma unroll
        for (int jj = 0; jj < 16; ++jj) {
            const int cp = c + jj;
            const int wb = cp & 31;
            const int kloc = (cp & ~31) | (((wb >> 3) & 3) << 2) | (((wb >> 2) & 1) << 4) | (wb & 3);
            val[jj] = T[kloc][row];
        }
        __bf16* dst = Vp + base + (size_t)row * 2048 + lb * 64 + c;
        *reinterpret_cast<bf16x8*>(dst)     = *reinterpret_cast<bf16x8*>(&val[0]);
        *reinterpret_cast<bf16x8*>(dst + 8) = *reinterpret_cast<bf16x8*>(&val[8]);
    }
}

// ---------------- flash attention: 8 waves (512 thr), QBLK=128, NO KV-split ----------
// grid (bh=32, qb=16) = 512 blocks = exact 2/CU at (512,6); each block runs all 32
// kb-tiles and writes normalized bf16 output directly (inv = 1/ls, ls rows = Oa rows).
// NOTE: (512,6) + natural bh-fastest dispatch order is load-bearing (R15 lesson).
__global__ __launch_bounds__(512, 6) void attn_kernel(
    const __bf16* __restrict__ Q, const __bf16* __restrict__ K,
    const __bf16* __restrict__ Vp, const __bf16* __restrict__ biasB,
    __bf16* __restrict__ Octx) {
    __shared__ __bf16 KVs[2][2][64 * 64];   // [buf][K/V]; LDS[row][c]=G[row][c^((row&7)<<4)]
    const int bh = blockIdx.x, qb = blockIdx.y;
    const int tid = threadIdx.x;
    const int w = tid >> 6, l = tid & 63;
    const int lr = l & 15, lg = l >> 4;
    const int rmask = (lr & 7) << 4;
    const int b = bh >> 4, h = bh & 15;
    const size_t base = (size_t)bh * LL * DD;

    const int gq = qb * 128 + w * 16 + lr;
    bf16x8 qf[2];
    qf[0] = *reinterpret_cast<const bf16x8*>(Q + base + (size_t)gq * 64 + lg * 8);
    qf[1] = *reinterpret_cast<const bf16x8*>(Q + base + (size_t)gq * 64 + 32 + lg * 8);
    const __bf16* brow = biasB + (size_t)gq * 2048 + lg * 4;

    bf16x8 ones;
#pragma unroll
    for (int j = 0; j < 8; ++j) ones[j] = (__bf16)1.0f;

    // staging: wave w covers rows [w*8, w*8+8); lane: row w*8+(l>>3), 8 elems at (l&7)*8
    const int srow = w * 8 + (l >> 3);
    const int sce  = (l & 7) * 8;                  // element col
    const int smask = (srow & 7) << 4;             // (l>>3)<<4
    const __bf16* kgbase = K  + base + (size_t)srow * 64   + sce;
    const __bf16* vgbase = Vp + base + (size_t)srow * 2048 + sce;

    bf16x8 k0, v0;
    auto stage_regs = [&](int kb) {
        k0 = *reinterpret_cast<const bf16x8*>(kgbase + (size_t)kb * 64 * 64);
        v0 = *reinterpret_cast<const bf16x8*>(vgbase + kb * 64);
    };
    auto write_lds = [&](int buf) {
        *reinterpret_cast<bf16x8*>((char*)KVs[buf][0] + srow * 128 + ((sce * 2) ^ smask)) = k0;
        *reinterpret_cast<bf16x8*>((char*)KVs[buf][1] + srow * 128 + ((sce * 2) ^ smask)) = v0;
    };

    stage_regs(0);
    write_lds(0);

    f32x4 Oa[4] = {};
    f32x4 ls = {};
    int cur = 0;

    bf16x4 bcur[4];
#pragma unroll
    for (int t = 0; t < 4; ++t)
        bcur[t] = *reinterpret_cast<const bf16x4*>(brow + t * 16);

    for (int kb = 0; kb < 32; ++kb) {
        __syncthreads();                    // buf[cur] published; buf[cur^1] free
        if (kb < 31) stage_regs(kb + 1);

        bf16x4 bnext[4];
        if (kb < 31) {
#pragma unroll
            for (int t = 0; t < 4; ++t)
                bnext[t] = *reinterpret_cast<const bf16x4*>(brow + (kb + 1) * 64 + t * 16);
        }

        const char* Kc = (const char*)KVs[cur][0];
        const char* Vc = (const char*)KVs[cur][1];

        // acc init = bias'(bf16); no cexp (cancels in O = sum(pv)/sum(p))
        f32x4 sa[4];
#pragma unroll
        for (int t = 0; t < 4; ++t)
#pragma unroll
            for (int r = 0; r < 4; ++r)
                sa[t][r] = (float)bcur[t][r];

        // S^T·log2e + bias' : lane q=lr, k = 16t+4lg+r
#pragma unroll
        for (int t = 0; t < 4; ++t) {
            const char* kr = Kc + (t * 16 + lr) * 128;
            bf16x8 kf0 = *reinterpret_cast<const bf16x8*>(kr + ((lg * 16) ^ rmask));
            bf16x8 kf1 = *reinterpret_cast<const bf16x8*>(kr + ((64 + lg * 16) ^ rmask));
            sa[t] = mfma_16x16x32(kf0, qf[0], sa[t]);
            sa[t] = mfma_16x16x32(kf1, qf[1], sa[t]);
        }

        // softmax: p = exp2(sa); pack lane-local values into A-operand slots
        float p[4][4];
#pragma unroll
        for (int t = 0; t < 4; ++t)
#pragma unroll
            for (int r = 0; r < 4; ++r)
                p[t][r] = exp2f(sa[t][r]);
        union Upa { unsigned u[4]; bf16x8 v; } pa0, pa1;
        pa0.u[0] = pk_bf16(p[0][0], p[0][1]); pa0.u[1] = pk_bf16(p[0][2], p[0][3]);
        pa0.u[2] = pk_bf16(p[1][0], p[1][1]); pa0.u[3] = pk_bf16(p[1][2], p[1][3]);
        pa1.u[0] = pk_bf16(p[2][0], p[2][1]); pa1.u[1] = pk_bf16(p[2][2], p[2][3]);
        pa1.u[2] = pk_bf16(p[3][0], p[3][1]); pa1.u[3] = pk_bf16(p[3][2], p[3][3]);

        // row-sum via MFMA (B = ones): ls rows = Oa rows
        ls = mfma_16x16x32(pa0.v, ones, ls);
        ls = mfma_16x16x32(pa1.v, ones, ls);

        // O += P·V : V pre-permuted globally -> contiguous b128 reads (same pattern as K)
#pragma unroll
        for (int t = 0; t < 4; ++t) {
            const char* vr = Vc + (t * 16 + lr) * 128;
            bf16x8 vf0 = *reinterpret_cast<const bf16x8*>(vr + ((lg * 16) ^ rmask));
            bf16x8 vf1 = *reinterpret_cast<const bf16x8*>(vr + ((64 + lg * 16) ^ rmask));
            Oa[t] = mfma_16x16x32(pa0.v, vf0, Oa[t]);
            Oa[t] = mfma_16x16x32(pa1.v, vf1, Oa[t]);
        }

        if (kb < 31) {
            write_lds(cur ^ 1);             // write-late; dep on loads forces vmcnt
#pragma unroll
            for (int t = 0; t < 4; ++t) bcur[t] = bnext[t];
        }
        cur ^= 1;
    }

    // normalized bf16 output direct (inv from MFMA row-sum; ls rows == Oa rows)
    float inv[4];
#pragma unroll
    for (int r = 0; r < 4; ++r) inv[r] = 1.0f / ls[r];
#pragma unroll
    for (int t = 0; t < 4; ++t)
#pragma unroll
        for (int r = 0; r < 4; ++r) {
            const int row = qb * 128 + w * 16 + lg * 4 + r;
            Octx[((size_t)(b * 2048 + row)) * 1024 + h * 64 + t * 16 + lr] =
                (__bf16)(Oa[t][r] * inv[r]);
        }
}

// ---------------- launch ----------------
extern "C" void kernel_launch(void* const* d_in, const int* in_sizes, int n_in,
                              void* d_out, int out_size, void* d_ws, size_t ws_size,
                              hipStream_t stream) {
    const float* x         = (const float*)d_in[0];
    const float* attn_bias = (const float*)d_in[1];
    const float* W_qkv     = (const float*)d_in[2];
    const float* q_bias    = (const float*)d_in[3];
    const float* v_bias    = (const float*)d_in[4];
    const float* scale_mul = (const float*)d_in[5];
    const float* W_proj    = (const float*)d_in[6];
    const float* b_proj    = (const float*)d_in[7];
    float* out = (float*)d_out;

    char* ws = (char*)d_ws;
    size_t off = 0;
    auto alloc = [&](size_t bytes) {
        void* p = ws + off;
        off = (off + bytes + 255) & ~(size_t)255;
        return p;
    };
    __bf16* Vw      = (__bf16*)alloc((size_t)BB * HH * LL * DD * 2);   //  8 MB
    __bf16* xb      = (__bf16*)alloc((size_t)4096 * 1024 * 2);         //  8 MB
    __bf16* wqkvb   = (__bf16*)alloc((size_t)3072 * 1024 * 2);         //  6 MB
    __bf16* wprojb  = (__bf16*)alloc((size_t)1024 * 1024 * 2);         //  2 MB
    __bf16* Qw      = (__bf16*)alloc((size_t)BB * HH * LL * DD * 2);   //  8 MB
    __bf16* Kw      = (__bf16*)alloc((size_t)BB * HH * LL * DD * 2);   //  8 MB
    __bf16* Oc      = (__bf16*)alloc((size_t)4096 * 1024 * 2);         //  8 MB
    __bf16* biasB   = (__bf16*)alloc((size_t)2048 * 2048 * 2);         //  8 MB
    __bf16* Vp      = (__bf16*)alloc((size_t)BB * HH * LL * DD * 2);   //  8 MB

    cvt3_kernel<<<8192, 256, 0, stream>>>(x, W_qkv, W_proj, xb, wqkvb, wprojb);

    gemm_qkv_fused_kernel<<<dim3(32, 24), 256, 0, stream>>>(
        xb, wqkvb, q_bias, v_bias, scale_mul, Qw, Kw, Vw);

    prep_kernel<<<3072, 256, 0, stream>>>(attn_bias, biasB, Vw, Vp);

    attn_kernel<<<dim3(32, 16), 512, 0, stream>>>(Qw, Kw, Vp, biasB, Oc);

    gemm_proj_kernel<<<dim3(32, 8), 256, 0, stream>>>(
        Oc, wprojb, out, b_proj, 4096, 1024, 1024);
}

// Round 20
// 163.297 us; speedup vs baseline: 1.3140x; 1.0260x over previous
//
#include <hip/hip_runtime.h>

// Pipeline (4 dispatches): cvt3+bias_prep -> GEMM qkv + fused bias/l2norm/scale/split
//   (V written directly transposed+permuted) -> flash attn (8 waves QBLK=128, no split)
//   -> GEMM proj(f32+bias)
// B=2 L=2048 C=1024 H=16 D=64. All matmuls bf16 MFMA 16x16x32, f32 accumulate.

typedef __bf16 bf16x8 __attribute__((ext_vector_type(8)));
typedef __bf16 bf16x4 __attribute__((ext_vector_type(4)));
typedef float  f32x4  __attribute__((ext_vector_type(4)));

#define BB 2
#define LL 2048
#define CC 1024
#define HH 16
#define DD 64
#define LOG2E 1.44269504088896f

__device__ __forceinline__ f32x4 mfma_16x16x32(bf16x8 a, bf16x8 b, f32x4 c) {
    return __builtin_amdgcn_mfma_f32_16x16x32_bf16(a, b, c, 0, 0, 0);
}

// async global->LDS, 16B per lane; LDS dest = wave-uniform base + lane*16
__device__ __forceinline__ void gload_lds16(const __bf16* g, __bf16* lds) {
    __builtin_amdgcn_global_load_lds(
        (const __attribute__((address_space(1))) unsigned int*)g,
        (__attribute__((address_space(3))) unsigned int*)lds,
        16, 0, 0);
}

__device__ __forceinline__ unsigned pk_bf16(float a, float b) {
    unsigned short ua = __builtin_bit_cast(unsigned short, (__bf16)a);
    unsigned short ub = __builtin_bit_cast(unsigned short, (__bf16)b);
    return (unsigned)ua | ((unsigned)ub << 16);
}

// ---------------- merged: f32->bf16 cvt (blocks 0..8191) + bias_prep (8192..10239) -------
__global__ __launch_bounds__(256) void cvt3b_kernel(
    const float* __restrict__ x, const float* __restrict__ wq, const float* __restrict__ wp,
    const float* __restrict__ bias,
    __bf16* __restrict__ xb, __bf16* __restrict__ wqb, __bf16* __restrict__ wpb,
    __bf16* __restrict__ bias_bf) {
    const int tid = threadIdx.x;
    if (blockIdx.x < 8192) {
        const int i = blockIdx.x * 256 + tid;   // f32x4 index, 2097152 total
        const float* src; __bf16* dst; int off;
        if (i < 1048576)      { src = x;  dst = xb;  off = i; }
        else if (i < 1835008) { src = wq; dst = wqb; off = i - 1048576; }
        else                  { src = wp; dst = wpb; off = i - 1835008; }
        float4 v = reinterpret_cast<const float4*>(src)[off];
        bf16x4 o;
        o[0] = (__bf16)v.x; o[1] = (__bf16)v.y; o[2] = (__bf16)v.z; o[3] = (__bf16)v.w;
        reinterpret_cast<bf16x4*>(dst)[off] = o;
    } else {
        __shared__ float wmax[4];
        const int l = blockIdx.x - 8192;        // bias row 0..2047
        const int w = tid >> 6;
        float4 a = reinterpret_cast<const float4*>(bias + (size_t)l * 2048)[tid];
        float4 b = reinterpret_cast<const float4*>(bias + (size_t)l * 2048 + 1024)[tid];
        float m = fmaxf(fmaxf(fmaxf(a.x, a.y), fmaxf(a.z, a.w)),
                        fmaxf(fmaxf(b.x, b.y), fmaxf(b.z, b.w)));
#pragma unroll
        for (int off = 1; off < 64; off <<= 1) m = fmaxf(m, __shfl_xor(m, off, 64));
        if ((tid & 63) == 0) wmax[w] = m;
        __syncthreads();
        float M = fmaxf(fmaxf(wmax[0], wmax[1]), fmaxf(wmax[2], wmax[3]));
        bf16x4 o0, o1;
        o0[0] = (__bf16)((a.x - M) * LOG2E); o0[1] = (__bf16)((a.y - M) * LOG2E);
        o0[2] = (__bf16)((a.z - M) * LOG2E); o0[3] = (__bf16)((a.w - M) * LOG2E);
        o1[0] = (__bf16)((b.x - M) * LOG2E); o1[1] = (__bf16)((b.y - M) * LOG2E);
        o1[2] = (__bf16)((b.z - M) * LOG2E); o1[3] = (__bf16)((b.w - M) * LOG2E);
        reinterpret_cast<bf16x4*>(bias_bf + (size_t)l * 2048)[tid] = o0;
        reinterpret_cast<bf16x4*>(bias_bf + (size_t)l * 2048 + 1024)[tid] = o1;
    }
}

// ---------------- QKV GEMM + fused bias/l2norm/scale/split; V written directly as
//                  Vp (B,H,D,perm(L)): pos = (k[3:2]<<3)|(k[4]<<2)|k[1:0] per 32-block ----
__global__ __launch_bounds__(256) void gemm_qkv_fused_kernel(
    const __bf16* __restrict__ A, const __bf16* __restrict__ Bm,
    const float* __restrict__ q_bias, const float* __restrict__ v_bias,
    const float* __restrict__ scale_mul,
    __bf16* __restrict__ Qw, __bf16* __restrict__ Kw, __bf16* __restrict__ Vp) {
    __shared__ __bf16 As[128 * 64];   // LDS[row][c] = A[row][c ^ ((row&7)<<4)]  (byte view)
    __shared__ __bf16 Bs[128 * 64];
    const int tid = threadIdx.x;
    const int K = 1024;
    const int nwg = gridDim.x * gridDim.y;
    const int flat = blockIdx.y * gridDim.x + blockIdx.x;
    const int wg = (flat & 7) * (nwg >> 3) + (flat >> 3);
    const int m0 = (wg % gridDim.x) * 128, n0 = (wg / gridDim.x) * 128;
    const int w  = tid >> 6, l = tid & 63;
    const int wr = (w >> 1) * 64, wc = (w & 1) * 64;
    const int lr = l & 15, lg = l >> 4;
    const int rmask = (lr & 7) << 4;
    f32x4 acc[4][4] = {};
    const int lrow = l >> 3;
    const int celem = (((l & 7) ^ lrow) << 3);

    for (int kt = 0; kt < K; kt += 64) {
        __syncthreads();
#pragma unroll
        for (int i = 0; i < 4; ++i) {
            const int row = w * 32 + i * 8;
            gload_lds16(A + (size_t)(m0 + row + lrow) * K + kt + celem, &As[row * 64]);
            gload_lds16(Bm + (size_t)(n0 + row + lrow) * K + kt + celem, &Bs[row * 64]);
        }
        asm volatile("s_waitcnt vmcnt(0)" ::: "memory");
        __syncthreads();
#pragma unroll
        for (int kk = 0; kk < 2; ++kk) {
            bf16x8 af[4], bfr[4];
#pragma unroll
            for (int m = 0; m < 4; ++m)
                af[m] = *reinterpret_cast<const bf16x8*>(
                    (char*)As + (wr + m * 16 + lr) * 128 + ((kk * 64 + lg * 16) ^ rmask));
#pragma unroll
            for (int n = 0; n < 4; ++n)
                bfr[n] = *reinterpret_cast<const bf16x8*>(
                    (char*)Bs + (wc + n * 16 + lr) * 128 + ((kk * 64 + lg * 16) ^ rmask));
#pragma unroll
            for (int m = 0; m < 4; ++m)
#pragma unroll
                for (int n = 0; n < 4; ++n)
                    acc[m][n] = mfma_16x16x32(af[m], bfr[n], acc[m][n]);
        }
    }

    // ---- fused epilogue ----
    const int gcbase = n0 + wc;
    const int type = gcbase >> 10;           // 0=q, 1=k, 2=v
    const int h = (gcbase & 1023) >> 6;
    float qscale = 1.0f;
    if (type == 0) qscale = __expf(fminf(scale_mul[h], 4.60517019f)) * LOG2E;
    __bf16* dst = (type == 0) ? Qw : Kw;

#pragma unroll
    for (int m = 0; m < 4; ++m) {
        if (type != 1) {                     // q/v bias (k has zero bias)
            const float* bptr = (type == 0) ? q_bias : v_bias;
#pragma unroll
            for (int n = 0; n < 4; ++n) {
                float bv = bptr[(gcbase & 1023) + n * 16 + lr];
#pragma unroll
                for (int r = 0; r < 4; ++r) acc[m][n][r] += bv;
            }
        }
        const int rowg = m0 + wr + m * 16 + lg * 4;
        if (type < 2) {
            float rs[4];
#pragma unroll
            for (int r = 0; r < 4; ++r) {
                float ss = 0.f;
#pragma unroll
                for (int n = 0; n < 4; ++n) ss += acc[m][n][r] * acc[m][n][r];
                rs[r] = ss;
            }
#pragma unroll
            for (int off = 1; off < 16; off <<= 1)
#pragma unroll
                for (int r = 0; r < 4; ++r) rs[r] += __shfl_xor(rs[r], off, 64);
#pragma unroll
            for (int r = 0; r < 4; ++r)
                rs[r] = ((type == 0) ? qscale : 1.0f) / fmaxf(sqrtf(rs[r]), 1e-12f);
#pragma unroll
            for (int n = 0; n < 4; ++n) {
                const int d = n * 16 + lr;
#pragma unroll
                for (int r = 0; r < 4; ++r) {
                    const int row = rowg + r;
                    const int bb = row >> 11, ll = row & 2047;
                    dst[((size_t)((bb << 4) + h) * 2048 + ll) * 64 + d] =
                        (__bf16)(acc[m][n][r] * rs[r]);
                }
            }
        } else {
            // V: direct transposed+permuted write. rowg%4==0, so the 4 rows map to
            // 4 consecutive Vp positions: posb = (k3_2<<3)|(k4<<2), +r.
            const int bb = rowg >> 11, ll0 = rowg & 2047;
            const int posb = (ll0 & ~31) | (((ll0 >> 2) & 3) << 3) | (((ll0 >> 4) & 1) << 2);
#pragma unroll
            for (int n = 0; n < 4; ++n) {
                const int d = n * 16 + lr;
                bf16x4 vv;
#pragma unroll
                for (int r = 0; r < 4; ++r) vv[r] = (__bf16)acc[m][n][r];
                *reinterpret_cast<bf16x4*>(
                    Vp + ((size_t)((bb << 4) + h) * 64 + d) * 2048 + posb) = vv;
            }
        }
    }
}

// ---------------- GEMM proj: C = A*B^T + bias (f32 out), m97 + XCD swz ----------
__global__ __launch_bounds__(256) void gemm_proj_kernel(
    const __bf16* __restrict__ A, const __bf16* __restrict__ Bm,
    float* __restrict__ Cf, const float* __restrict__ bias, int M, int N, int K) {
    __shared__ __bf16 As[128 * 64];
    __shared__ __bf16 Bs[128 * 64];
    const int tid = threadIdx.x;
    const int nwg = gridDim.x * gridDim.y;
    const int flat = blockIdx.y * gridDim.x + blockIdx.x;
    const int wg = (flat & 7) * (nwg >> 3) + (flat >> 3);
    const int m0 = (wg % gridDim.x) * 128, n0 = (wg / gridDim.x) * 128;
    const int w  = tid >> 6, l = tid & 63;
    const int wr = (w >> 1) * 64, wc = (w & 1) * 64;
    const int lr = l & 15, lg = l >> 4;
    const int rmask = (lr & 7) << 4;
    f32x4 acc[4][4] = {};
    const int lrow = l >> 3;
    const int celem = (((l & 7) ^ lrow) << 3);

    for (int kt = 0; kt < K; kt += 64) {
        __syncthreads();
#pragma unroll
        for (int i = 0; i < 4; ++i) {
            const int row = w * 32 + i * 8;
            gload_lds16(A + (size_t)(m0 + row + lrow) * K + kt + celem, &As[row * 64]);
            gload_lds16(Bm + (size_t)(n0 + row + lrow) * K + kt + celem, &Bs[row * 64]);
        }
        asm volatile("s_waitcnt vmcnt(0)" ::: "memory");
        __syncthreads();
#pragma unroll
        for (int kk = 0; kk < 2; ++kk) {
            bf16x8 af[4], bfr[4];
#pragma unroll
            for (int m = 0; m < 4; ++m)
                af[m] = *reinterpret_cast<const bf16x8*>(
                    (char*)As + (wr + m * 16 + lr) * 128 + ((kk * 64 + lg * 16) ^ rmask));
#pragma unroll
            for (int n = 0; n < 4; ++n)
                bfr[n] = *reinterpret_cast<const bf16x8*>(
                    (char*)Bs + (wc + n * 16 + lr) * 128 + ((kk * 64 + lg * 16) ^ rmask));
#pragma unroll
            for (int m = 0; m < 4; ++m)
#pragma unroll
                for (int n = 0; n < 4; ++n)
                    acc[m][n] = mfma_16x16x32(af[m], bfr[n], acc[m][n]);
        }
    }
#pragma unroll
    for (int m = 0; m < 4; ++m)
#pragma unroll
        for (int n = 0; n < 4; ++n) {
            const int row = m0 + wr + m * 16 + lg * 4;
            const int col = n0 + wc + n * 16 + lr;
#pragma unroll
            for (int r = 0; r < 4; ++r)
                Cf[(size_t)(row + r) * N + col] = acc[m][n][r] + bias[col];
        }
}

// ---------------- flash attention: 8 waves (512 thr), QBLK=128, NO KV-split ----------
// grid (bh=32, qb=16) = 512 blocks = exact 2/CU at (512,6); each block runs all 32
// kb-tiles and writes normalized bf16 output directly (inv = 1/ls, ls rows = Oa rows).
// NOTE: (512,6) + natural bh-fastest dispatch order is load-bearing (R15 lesson).
__global__ __launch_bounds__(512, 6) void attn_kernel(
    const __bf16* __restrict__ Q, const __bf16* __restrict__ K,
    const __bf16* __restrict__ Vp, const __bf16* __restrict__ biasB,
    __bf16* __restrict__ Octx) {
    __shared__ __bf16 KVs[2][2][64 * 64];   // [buf][K/V]; LDS[row][c]=G[row][c^((row&7)<<4)]
    const int bh = blockIdx.x, qb = blockIdx.y;
    const int tid = threadIdx.x;
    const int w = tid >> 6, l = tid & 63;
    const int lr = l & 15, lg = l >> 4;
    const int rmask = (lr & 7) << 4;
    const int b = bh >> 4, h = bh & 15;
    const size_t base = (size_t)bh * LL * DD;

    const int gq = qb * 128 + w * 16 + lr;
    bf16x8 qf[2];
    qf[0] = *reinterpret_cast<const bf16x8*>(Q + base + (size_t)gq * 64 + lg * 8);
    qf[1] = *reinterpret_cast<const bf16x8*>(Q + base + (size_t)gq * 64 + 32 + lg * 8);
    const __bf16* brow = biasB + (size_t)gq * 2048 + lg * 4;

    bf16x8 ones;
#pragma unroll
    for (int j = 0; j < 8; ++j) ones[j] = (__bf16)1.0f;

    // staging: wave w covers rows [w*8, w*8+8); lane: row w*8+(l>>3), 8 elems at (l&7)*8
    const int srow = w * 8 + (l >> 3);
    const int sce  = (l & 7) * 8;                  // element col
    const int smask = (srow & 7) << 4;             // (l>>3)<<4
    const __bf16* kgbase = K  + base + (size_t)srow * 64   + sce;
    const __bf16* vgbase = Vp + base + (size_t)srow * 2048 + sce;

    bf16x8 k0, v0;
    auto stage_regs = [&](int kb) {
        k0 = *reinterpret_cast<const bf16x8*>(kgbase + (size_t)kb * 64 * 64);
        v0 = *reinterpret_cast<const bf16x8*>(vgbase + kb * 64);
    };
    auto write_lds = [&](int buf) {
        *reinterpret_cast<bf16x8*>((char*)KVs[buf][0] + srow * 128 + ((sce * 2) ^ smask)) = k0;
        *reinterpret_cast<bf16x8*>((char*)KVs[buf][1] + srow * 128 + ((sce * 2) ^ smask)) = v0;
    };

    stage_regs(0);
    write_lds(0);

    f32x4 Oa[4] = {};
    f32x4 ls = {};
    int cur = 0;

    bf16x4 bcur[4];
#pragma unroll
    for (int t = 0; t < 4; ++t)
        bcur[t] = *reinterpret_cast<const bf16x4*>(brow + t * 16);

    for (int kb = 0; kb < 32; ++kb) {
        __syncthreads();                    // buf[cur] published; buf[cur^1] free
        if (kb < 31) stage_regs(kb + 1);

        bf16x4 bnext[4];
        if (kb < 31) {
#pragma unroll
            for (int t = 0; t < 4; ++t)
                bnext[t] = *reinterpret_cast<const bf16x4*>(brow + (kb + 1) * 64 + t * 16);
        }

        const char* Kc = (const char*)KVs[cur][0];
        const char* Vc = (const char*)KVs[cur][1];

        // acc init = bias'(bf16); no cexp (cancels in O = sum(pv)/sum(p))
        f32x4 sa[4];
#pragma unroll
        for (int t = 0; t < 4; ++t)
#pragma unroll
            for (int r = 0; r < 4; ++r)
                sa[t][r] = (float)bcur[t][r];

        // S^T·log2e + bias' : lane q=lr, k = 16t+4lg+r
#pragma unroll
        for (int t = 0; t < 4; ++t) {
            const char* kr = Kc + (t * 16 + lr) * 128;
            bf16x8 kf0 = *reinterpret_cast<const bf16x8*>(kr + ((lg * 16) ^ rmask));
            bf16x8 kf1 = *reinterpret_cast<const bf16x8*>(kr + ((64 + lg * 16) ^ rmask));
            sa[t] = mfma_16x16x32(kf0, qf[0], sa[t]);
            sa[t] = mfma_16x16x32(kf1, qf[1], sa[t]);
        }

        // softmax: p = exp2(sa); pack lane-local values into A-operand slots
        float p[4][4];
#pragma unroll
        for (int t = 0; t < 4; ++t)
#pragma unroll
            for (int r = 0; r < 4; ++r)
                p[t][r] = exp2f(sa[t][r]);
        union Upa { unsigned u[4]; bf16x8 v; } pa0, pa1;
        pa0.u[0] = pk_bf16(p[0][0], p[0][1]); pa0.u[1] = pk_bf16(p[0][2], p[0][3]);
        pa0.u[2] = pk_bf16(p[1][0], p[1][1]); pa0.u[3] = pk_bf16(p[1][2], p[1][3]);
        pa1.u[0] = pk_bf16(p[2][0], p[2][1]); pa1.u[1] = pk_bf16(p[2][2], p[2][3]);
        pa1.u[2] = pk_bf16(p[3][0], p[3][1]); pa1.u[3] = pk_bf16(p[3][2], p[3][3]);

        // row-sum via MFMA (B = ones): ls rows = Oa rows
        ls = mfma_16x16x32(pa0.v, ones, ls);
        ls = mfma_16x16x32(pa1.v, ones, ls);

        // O += P·V : V pre-permuted globally -> contiguous b128 reads (same pattern as K)
#pragma unroll
        for (int t = 0; t < 4; ++t) {
            const char* vr = Vc + (t * 16 + lr) * 128;
            bf16x8 vf0 = *reinterpret_cast<const bf16x8*>(vr + ((lg * 16) ^ rmask));
            bf16x8 vf1 = *reinterpret_cast<const bf16x8*>(vr + ((64 + lg * 16) ^ rmask));
            Oa[t] = mfma_16x16x32(pa0.v, vf0, Oa[t]);
            Oa[t] = mfma_16x16x32(pa1.v, vf1, Oa[t]);
        }

        if (kb < 31) {
            write_lds(cur ^ 1);             // write-late; dep on loads forces vmcnt
#pragma unroll
            for (int t = 0; t < 4; ++t) bcur[t] = bnext[t];
        }
        cur ^= 1;
    }

    // normalized bf16 output direct (inv from MFMA row-sum; ls rows == Oa rows)
    float inv[4];
#pragma unroll
    for (int r = 0; r < 4; ++r) inv[r] = 1.0f / ls[r];
#pragma unroll
    for (int t = 0; t < 4; ++t)
#pragma unroll
        for (int r = 0; r < 4; ++r) {
            const int row = qb * 128 + w * 16 + lg * 4 + r;
            Octx[((size_t)(b * 2048 + row)) * 1024 + h * 64 + t * 16 + lr] =
                (__bf16)(Oa[t][r] * inv[r]);
        }
}

// ---------------- launch ----------------
extern "C" void kernel_launch(void* const* d_in, const int* in_sizes, int n_in,
                              void* d_out, int out_size, void* d_ws, size_t ws_size,
                              hipStream_t stream) {
    const float* x         = (const float*)d_in[0];
    const float* attn_bias = (const float*)d_in[1];
    const float* W_qkv     = (const float*)d_in[2];
    const float* q_bias    = (const float*)d_in[3];
    const float* v_bias    = (const float*)d_in[4];
    const float* scale_mul = (const float*)d_in[5];
    const float* W_proj    = (const float*)d_in[6];
    const float* b_proj    = (const float*)d_in[7];
    float* out = (float*)d_out;

    char* ws = (char*)d_ws;
    size_t off = 0;
    auto alloc = [&](size_t bytes) {
        void* p = ws + off;
        off = (off + bytes + 255) & ~(size_t)255;
        return p;
    };
    __bf16* xb      = (__bf16*)alloc((size_t)4096 * 1024 * 2);         //  8 MB
    __bf16* wqkvb   = (__bf16*)alloc((size_t)3072 * 1024 * 2);         //  6 MB
    __bf16* wprojb  = (__bf16*)alloc((size_t)1024 * 1024 * 2);         //  2 MB
    __bf16* Qw      = (__bf16*)alloc((size_t)BB * HH * LL * DD * 2);   //  8 MB
    __bf16* Kw      = (__bf16*)alloc((size_t)BB * HH * LL * DD * 2);   //  8 MB
    __bf16* Oc      = (__bf16*)alloc((size_t)4096 * 1024 * 2);         //  8 MB
    __bf16* biasB   = (__bf16*)alloc((size_t)2048 * 2048 * 2);         //  8 MB
    __bf16* Vp      = (__bf16*)alloc((size_t)BB * HH * LL * DD * 2);   //  8 MB

    cvt3b_kernel<<<10240, 256, 0, stream>>>(x, W_qkv, W_proj, attn_bias,
                                            xb, wqkvb, wprojb, biasB);

    gemm_qkv_fused_kernel<<<dim3(32, 24), 256, 0, stream>>>(
        xb, wqkvb, q_bias, v_bias, scale_mul, Qw, Kw, Vp);

    attn_kernel<<<dim3(32, 16), 512, 0, stream>>>(Qw, Kw, Vp, biasB, Oc);

    gemm_proj_kernel<<<dim3(32, 8), 256, 0, stream>>>(
        Oc, wprojb, out, b_proj, 4096, 1024, 1024);
}